// Round 1
// baseline (1931.974 us; speedup 1.0000x reference)
//
#include <hip/hip_runtime.h>
#include <hip/hip_bf16.h>

#define N_NODES 40960
#define N_SESS  4096
#define N_EDGES 81920
#define DIM     64
#define HID     100
#define VITEMS  50000

// ---------------------------------------------------------------------------
// Generic fp32 tiled GEMM: C[M,N] = A[M,K] @ B[K,N] (+bias) (optional relu)
// Requires K%4==0, N%4==0, lda/ldb/ldc %4==0 (true for all uses here).
// BM=BN=64, BK=32, 256 threads, TM=TN=4.
// ---------------------------------------------------------------------------
__global__ __launch_bounds__(256)
void gemm_f32(const float* __restrict__ A, int lda,
              const float* __restrict__ B, int ldb,
              const float* __restrict__ bias,
              float* __restrict__ C, int ldc,
              int M, int N, int K, int relu)
{
    __shared__ float As[32][68];   // [k][m], pad 68 keeps float4 reads aligned + conflict-free
    __shared__ float Bs[32][68];   // [k][n]
    const int tid = threadIdx.x;
    const int tm = tid & 15;
    const int tn = tid >> 4;
    const int m0 = blockIdx.y * 64;
    const int n0 = blockIdx.x * 64;
    float acc[4][4] = {};

    for (int k0 = 0; k0 < K; k0 += 32) {
        // stage A tile 64x32 (512 float4, 2/thread), store transposed As[k][m]
        #pragma unroll
        for (int i = 0; i < 2; ++i) {
            int f4  = tid + i * 256;
            int row = f4 >> 3;
            int kc  = (f4 & 7) << 2;
            float4 v = make_float4(0.f, 0.f, 0.f, 0.f);
            int gm = m0 + row, gk = k0 + kc;
            if (gm < M && gk < K)
                v = *reinterpret_cast<const float4*>(&A[(size_t)gm * lda + gk]);
            As[kc + 0][row] = v.x;
            As[kc + 1][row] = v.y;
            As[kc + 2][row] = v.z;
            As[kc + 3][row] = v.w;
        }
        // stage B tile 32x64 (512 float4, 2/thread)
        #pragma unroll
        for (int i = 0; i < 2; ++i) {
            int f4  = tid + i * 256;
            int row = f4 >> 4;
            int nc  = (f4 & 15) << 2;
            float4 v = make_float4(0.f, 0.f, 0.f, 0.f);
            int gk = k0 + row, gn = n0 + nc;
            if (gk < K && gn < N)
                v = *reinterpret_cast<const float4*>(&B[(size_t)gk * ldb + gn]);
            *reinterpret_cast<float4*>(&Bs[row][nc]) = v;
        }
        __syncthreads();
        #pragma unroll
        for (int kk = 0; kk < 32; ++kk) {
            float4 a4 = *reinterpret_cast<const float4*>(&As[kk][tm << 2]);
            float4 b4 = *reinterpret_cast<const float4*>(&Bs[kk][tn << 2]);
            float av[4] = {a4.x, a4.y, a4.z, a4.w};
            float bv[4] = {b4.x, b4.y, b4.z, b4.w};
            #pragma unroll
            for (int i = 0; i < 4; ++i)
                #pragma unroll
                for (int j = 0; j < 4; ++j)
                    acc[i][j] += av[i] * bv[j];
        }
        __syncthreads();
    }

    const int gn0 = n0 + (tn << 2);
    if (gn0 >= N) return;
    float4 bi = make_float4(0.f, 0.f, 0.f, 0.f);
    if (bias) bi = *reinterpret_cast<const float4*>(&bias[gn0]);
    #pragma unroll
    for (int i = 0; i < 4; ++i) {
        int gm = m0 + (tm << 2) + i;
        if (gm >= M) continue;
        float4 o = make_float4(acc[i][0] + bi.x, acc[i][1] + bi.y,
                               acc[i][2] + bi.z, acc[i][3] + bi.w);
        if (relu) {
            o.x = fmaxf(o.x, 0.f); o.y = fmaxf(o.y, 0.f);
            o.z = fmaxf(o.z, 0.f); o.w = fmaxf(o.w, 0.f);
        }
        *reinterpret_cast<float4*>(&C[(size_t)gm * ldc + gn0]) = o;
    }
}

// h0[n,j] = b_msg[j] + price[n]*W_msg[0,j] + sum of 5 projected-table gathers
__global__ void h0_gather(const float* __restrict__ price,
                          const int* __restrict__ cat, const int* __restrict__ sub,
                          const int* __restrict__ elem, const int* __restrict__ brand,
                          const int* __restrict__ pid,
                          const float* __restrict__ Wmsg, const float* __restrict__ b_msg,
                          const float* __restrict__ Pm, float* __restrict__ h0)
{
    int idx = blockIdx.x * 256 + threadIdx.x;
    if (idx >= N_NODES * HID) return;
    int n = idx / HID, j = idx - n * HID;
    float v = b_msg[j] + price[n] * Wmsg[j];           // W_msg row 0 (price)
    v += Pm[(size_t)(        cat[n]) * HID + j];
    v += Pm[(size_t)( 256 +  sub[n]) * HID + j];
    v += Pm[(size_t)(1280 + elem[n]) * HID + j];
    v += Pm[(size_t)(3328 + brand[n]) * HID + j];
    v += Pm[(size_t)(7424 +  pid[n]) * HID + j];
    h0[idx] = v;
}

__global__ void deg_count(const int* __restrict__ dst, float* __restrict__ deg)
{
    int e = blockIdx.x * 256 + threadIdx.x;
    if (e < N_EDGES) atomicAdd(&deg[dst[e]], 1.0f);
}

__global__ void inv_deg_k(float* __restrict__ deg)
{
    int n = blockIdx.x * 256 + threadIdx.x;
    if (n < N_NODES) {
        float d = deg[n];
        deg[n] = d > 0.f ? 1.0f / d : 0.0f;
    }
}

__global__ void msg_scatter(const int* __restrict__ src, const int* __restrict__ dst,
                            const float* __restrict__ h0, float* __restrict__ msg)
{
    int idx = blockIdx.x * 256 + threadIdx.x;
    if (idx >= N_EDGES * HID) return;
    int e = idx / HID, j = idx - e * HID;
    atomicAdd(&msg[(size_t)dst[e] * HID + j], h0[(size_t)src[e] * HID + j]);
}

__global__ void msg_scale(const float* __restrict__ inv_deg, float* __restrict__ msg)
{
    int idx = blockIdx.x * 256 + threadIdx.x;
    if (idx >= N_NODES * HID) return;
    int n = idx / HID;
    msg[idx] *= inv_deg[n];
}

// GRU gates for one chunk of 10240 nodes; h updated in place.
__global__ void gru_gates(const float* __restrict__ gi, const float* __restrict__ gh,
                          float* __restrict__ h)
{
    int idx = blockIdx.x * 256 + threadIdx.x;
    if (idx >= 10240 * HID) return;
    int nl = idx / HID, j = idx - nl * HID;
    float ir  = gi[nl * 300 + j],        hr = gh[nl * 300 + j];
    float iz  = gi[nl * 300 + 100 + j],  hz = gh[nl * 300 + 100 + j];
    float in_ = gi[nl * 300 + 200 + j],  hn = gh[nl * 300 + 200 + j];
    float r  = 1.f / (1.f + expf(-(ir + hr)));
    float z  = 1.f / (1.f + expf(-(iz + hz)));
    float nn = tanhf(in_ + r * hn);
    float hv = h[idx];
    h[idx] = (1.f - z) * nn + z * hv;
}

__global__ void last_idx_k(const int* __restrict__ batch, int* __restrict__ last_idx)
{
    int n = blockIdx.x * 256 + threadIdx.x;
    if (n < N_NODES) atomicMax(&last_idx[batch[n]], n);
}

// last[s,:] = x[last_idx[s]] @ W_last + b_last ; one wave per session
__global__ __launch_bounds__(256)
void last_proj(const int* __restrict__ last_idx, const float* __restrict__ price,
               const int* __restrict__ cat, const int* __restrict__ sub,
               const int* __restrict__ elem, const int* __restrict__ brand,
               const int* __restrict__ pid,
               const float* __restrict__ Ecat, const float* __restrict__ Esub,
               const float* __restrict__ Eelem, const float* __restrict__ Ebrand,
               const float* __restrict__ Eitem,
               const float* __restrict__ W_last, const float* __restrict__ b_last,
               float* __restrict__ last)
{
    int s = blockIdx.x * 4 + (threadIdx.x >> 6);
    int l = threadIdx.x & 63;
    int n = last_idx[s];
    int ci = cat[n] * DIM, si = sub[n] * DIM, ei = elem[n] * DIM;
    int bi = brand[n] * DIM, pi = pid[n] * DIM;
    float acc0 = 0.f, acc1 = 0.f;
    for (int k = 0; k < 321; ++k) {
        float xk;
        if (k == 0)       xk = price[n];
        else if (k < 65)  xk = Ecat[ci + k - 1];
        else if (k < 129) xk = Esub[si + k - 65];
        else if (k < 193) xk = Eelem[ei + k - 129];
        else if (k < 257) xk = Ebrand[bi + k - 193];
        else              xk = Eitem[pi + k - 257];
        acc0 += xk * W_last[k * HID + l];
        if (l < HID - 64) acc1 += xk * W_last[k * HID + 64 + l];
    }
    last[s * HID + l] = acc0 + b_last[l];
    if (l < HID - 64) last[s * HID + 64 + l] = acc1 + b_last[64 + l];
}

__global__ void add_last(const int* __restrict__ batch, const float* __restrict__ last,
                         float* __restrict__ h)
{
    int idx = blockIdx.x * 256 + threadIdx.x;
    if (idx >= N_NODES * HID) return;
    int n = idx / HID, j = idx - n * HID;
    h[idx] += last[(size_t)batch[n] * HID + j];
}

// gate[n] = dot(relu_row, W_g2) + b_g2 ; also session-max via ordered-uint atomicMax
__global__ __launch_bounds__(256)
void gate_reduce(const float* __restrict__ g1, const float* __restrict__ W_g2,
                 const float* __restrict__ b_g2, const int* __restrict__ batch,
                 float* __restrict__ gate, unsigned* __restrict__ gmax)
{
    int n = blockIdx.x * 4 + (threadIdx.x >> 6);
    int l = threadIdx.x & 63;
    float s = g1[(size_t)n * HID + l] * W_g2[l];
    if (l < HID - 64) s += g1[(size_t)n * HID + 64 + l] * W_g2[64 + l];
    #pragma unroll
    for (int off = 32; off > 0; off >>= 1) s += __shfl_xor(s, off, 64);
    if (l == 0) {
        float gt = s + b_g2[0];
        gate[n] = gt;
        unsigned u = __float_as_uint(gt);
        u = (u & 0x80000000u) ? ~u : (u | 0x80000000u);
        atomicMax(&gmax[batch[n]], u);
    }
}

__global__ void softmax_w(const int* __restrict__ batch, const unsigned* __restrict__ gmax,
                          float* __restrict__ gate, float* __restrict__ wsum)
{
    int n = blockIdx.x * 256 + threadIdx.x;
    if (n >= N_NODES) return;
    unsigned u = gmax[batch[n]];
    float gm = (u & 0x80000000u) ? __uint_as_float(u ^ 0x80000000u) : __uint_as_float(~u);
    float w = expf(gate[n] - gm);
    gate[n] = w;
    atomicAdd(&wsum[batch[n]], w);
}

__global__ void pooled_k(const int* __restrict__ batch, const float* __restrict__ gate,
                         const float* __restrict__ wsum, const float* __restrict__ h,
                         float* __restrict__ pooled)
{
    int idx = blockIdx.x * 256 + threadIdx.x;
    if (idx >= N_NODES * HID) return;
    int n = idx / HID, j = idx - n * HID;
    int b = batch[n];
    float alpha = gate[n] / wsum[b];
    atomicAdd(&pooled[(size_t)b * HID + j], alpha * h[idx]);
}

extern "C" void kernel_launch(void* const* d_in, const int* in_sizes, int n_in,
                              void* d_out, int out_size, void* d_ws, size_t ws_size,
                              hipStream_t stream)
{
    const float* price    = (const float*)d_in[0];
    const int*   cat      = (const int*)d_in[1];
    const int*   sub      = (const int*)d_in[2];
    const int*   elem     = (const int*)d_in[3];
    const int*   brand    = (const int*)d_in[4];
    const int*   pid      = (const int*)d_in[5];
    const int*   eidx     = (const int*)d_in[6];
    const int*   batch    = (const int*)d_in[7];
    const float* emb_cat  = (const float*)d_in[8];
    const float* emb_sub  = (const float*)d_in[9];
    const float* emb_elem = (const float*)d_in[10];
    const float* emb_brand= (const float*)d_in[11];
    const float* emb_item = (const float*)d_in[12];
    const float* W_msg    = (const float*)d_in[13];
    const float* b_msg    = (const float*)d_in[14];
    const float* W_ih     = (const float*)d_in[15];
    const float* W_hh     = (const float*)d_in[16];
    const float* b_ih     = (const float*)d_in[17];
    const float* b_hh     = (const float*)d_in[18];
    const float* W_last   = (const float*)d_in[19];
    const float* b_last   = (const float*)d_in[20];
    const float* W_g1     = (const float*)d_in[21];
    const float* b_g1     = (const float*)d_in[22];
    const float* W_g2     = (const float*)d_in[23];
    const float* b_g2     = (const float*)d_in[24];
    const float* W_fc     = (const float*)d_in[25];
    const float* b_fc     = (const float*)d_in[26];
    float* out = (float*)d_out;

    const int* src = eidx;
    const int* dst = eidx + N_EDGES;

    // ---- workspace layout (float offsets); zeroed region first ----
    float* w = (float*)d_ws;
    float*    msg    = w + 0;          // N*HID        = 4096000
    float*    deg    = w + 4096000;    // N            = 40960
    float*    wsum   = w + 4136960;    // S            = 4096
    float*    pooled = w + 4141056;    // S*HID        = 409600
    int*      lastix = (int*)(w + 4550656);      // S  = 4096
    unsigned* gmax   = (unsigned*)(w + 4554752); // S  = 4096
    // zero region total: 4558848 floats
    float*    Pm     = w + 4558848;    // 57424*HID    = 5742400
    float*    h0     = w + 10301248;   // N*HID        = 4096000
    float*    gi     = w + 14397248;   // 10240*300    = 3072000
    float*    gh     = w + 17469248;   // 10240*300    = 3072000
    float*    last   = w + 20541248;   // S*HID        = 409600
    float*    gate   = w + 20950848;   // N            = 40960
    // total: 20991808 floats = ~84 MB

    hipMemsetAsync(w, 0, (size_t)4558848 * sizeof(float), stream);

    dim3 blk(256);
    auto gemm = [&](const float* A, int lda, const float* B, int ldb,
                    const float* bias, float* C, int ldc, int M, int N, int K, int relu) {
        dim3 g((N + 63) / 64, (M + 63) / 64);
        hipLaunchKernelGGL(gemm_f32, g, blk, 0, stream, A, lda, B, ldb, bias, C, ldc, M, N, K, relu);
    };

    // ---- projected embedding tables for W_msg (row 0 = price handled in gather) ----
    gemm(emb_cat,   DIM, W_msg +   1 * HID, HID, nullptr, Pm +      0, HID,   256, HID, DIM, 0);
    gemm(emb_sub,   DIM, W_msg +  65 * HID, HID, nullptr, Pm +  25600, HID,  1024, HID, DIM, 0);
    gemm(emb_elem,  DIM, W_msg + 129 * HID, HID, nullptr, Pm + 128000, HID,  2048, HID, DIM, 0);
    gemm(emb_brand, DIM, W_msg + 193 * HID, HID, nullptr, Pm + 332800, HID,  4096, HID, DIM, 0);
    gemm(emb_item,  DIM, W_msg + 257 * HID, HID, nullptr, Pm + 742400, HID, VITEMS, HID, DIM, 0);

    // ---- h0 = x @ W_msg + b_msg via gathers ----
    h0_gather<<<16000, blk, 0, stream>>>(price, cat, sub, elem, brand, pid, W_msg, b_msg, Pm, h0);

    // ---- degree + mean aggregation ----
    deg_count<<<320, blk, 0, stream>>>(dst, deg);
    inv_deg_k<<<160, blk, 0, stream>>>(deg);
    msg_scatter<<<32000, blk, 0, stream>>>(src, dst, h0, msg);
    msg_scale<<<16000, blk, 0, stream>>>(deg, msg);

    // ---- GRU cell, 4 chunks of 10240 nodes ----
    for (int c = 0; c < 4; ++c) {
        size_t nb = (size_t)c * 10240;
        gemm(msg + nb * HID, HID, W_ih, 300, b_ih, gi, 300, 10240, 300, HID, 0);
        gemm(h0  + nb * HID, HID, W_hh, 300, b_hh, gh, 300, 10240, 300, HID, 0);
        gru_gates<<<4000, blk, 0, stream>>>(gi, gh, h0 + nb * HID);
    }

    // ---- last-node projection and broadcast add ----
    last_idx_k<<<160, blk, 0, stream>>>(batch, lastix);
    last_proj<<<1024, blk, 0, stream>>>(lastix, price, cat, sub, elem, brand, pid,
                                        emb_cat, emb_sub, emb_elem, emb_brand, emb_item,
                                        W_last, b_last, last);
    add_last<<<16000, blk, 0, stream>>>(batch, last, h0);

    // ---- attentional aggregation ----
    gemm(h0, HID, W_g1, HID, b_g1, msg /*reuse as gate1*/, HID, N_NODES, HID, HID, 1);
    gate_reduce<<<10240, blk, 0, stream>>>(msg, W_g2, b_g2, batch, gate, gmax);
    softmax_w<<<160, blk, 0, stream>>>(batch, gmax, gate, wsum);
    pooled_k<<<16000, blk, 0, stream>>>(batch, gate, wsum, h0, pooled);

    // ---- final scoring GEMM ----
    gemm(pooled, HID, W_fc, VITEMS, b_fc, out, VITEMS, N_SESS, VITEMS, HID, 0);
}